// Round 2
// baseline (385.584 us; speedup 1.0000x reference)
//
#include <hip/hip_runtime.h>

#define D_MODEL 512
#define NHEADS 8
#define DH 64
#define BATCH 2
#define SEQ 4096
#define MTOT (BATCH*SEQ)   // 8192

typedef __attribute__((ext_vector_type(8))) short bf16x8;
typedef __attribute__((ext_vector_type(4))) float f32x4;

__device__ __forceinline__ unsigned short f2b(float f) {
  unsigned int u = __float_as_uint(f);
  u = (u + 0x7fffu + ((u >> 16) & 1u)) >> 16;
  return (unsigned short)u;
}

__device__ __forceinline__ float fexp2(float x) {
  return __builtin_amdgcn_exp2f(x);   // v_exp_f32 (input already base-2)
}

// ---------------- conversion kernels ----------------

__global__ void cvt_x_kernel(const float* __restrict__ X,
                             unsigned short* __restrict__ Xb, int n) {
  int i = (blockIdx.x * blockDim.x + threadIdx.x) * 8;
  if (i >= n) return;
  const float4* s = (const float4*)(X + i);
  float4 v0 = s[0], v1 = s[1];
  union { bf16x8 v; unsigned short u[8]; } r;
  r.u[0] = f2b(v0.x); r.u[1] = f2b(v0.y); r.u[2] = f2b(v0.z); r.u[3] = f2b(v0.w);
  r.u[4] = f2b(v1.x); r.u[5] = f2b(v1.y); r.u[6] = f2b(v1.z); r.u[7] = f2b(v1.w);
  *(bf16x8*)(Xb + i) = r.v;
}

// W is [in=k][out=n] (512x512). Write Wt[n][k] bf16 so B-fragments read contiguous k.
__global__ void cvt_w_kernel(const float* __restrict__ W0, const float* __restrict__ W1,
                             const float* __restrict__ W2, const float* __restrict__ W3,
                             unsigned short* __restrict__ Wt) {
  const float* Ws[4] = {W0, W1, W2, W3};
  const float* W = Ws[blockIdx.y];
  int t = blockIdx.x * blockDim.x + threadIdx.x;   // 0..262143
  int k = t >> 9, n = t & 511;
  Wt[(size_t)blockIdx.y * (512*512) + (size_t)n * 512 + k] = f2b(W[t]);
}

// ---------------- 128x128 bf16 MFMA GEMM ----------------
// A: [8192][512] bf16 row-major. Wt: [512 n][512 k] bf16 (transposed weight).
// mode 0/1/2 -> bf16 head-split write into Q/K/V ([B,H,S,Dh], contiguous blocks of
// 4194304 elements starting at qkv). mode 3 -> fp32 write to outF ([8192][512]).
__global__ __launch_bounds__(256) void gemm128_kernel(
    const unsigned short* __restrict__ A,
    const unsigned short* __restrict__ WtAll,
    unsigned short* __restrict__ qkv,
    float* __restrict__ outF,
    int modeParam) {
  int mode = (modeParam < 0) ? (int)blockIdx.z : modeParam;
  const unsigned short* Wt = WtAll + (size_t)((modeParam < 0) ? blockIdx.z : 0) * (512*512);

  __shared__ __align__(16) unsigned short Alds[128][72];
  __shared__ __align__(16) unsigned short Blds[128][72];

  int t = threadIdx.x;
  int lane = t & 63, wave = t >> 6;
  int wr = wave >> 1, wc = wave & 1;
  int lr = lane & 15, lg = lane >> 4;
  int mBase = blockIdx.x * 128;
  int nBase = blockIdx.y * 128;

  f32x4 zero = {0.f, 0.f, 0.f, 0.f};
  f32x4 acc[4][4];
#pragma unroll
  for (int i = 0; i < 4; i++)
#pragma unroll
    for (int j = 0; j < 4; j++) acc[i][j] = zero;

  int seg = t & 7, r0 = t >> 3;

  for (int k0 = 0; k0 < 512; k0 += 64) {
#pragma unroll
    for (int p = 0; p < 4; ++p) {
      int row = r0 + p * 32;
      *(int4*)&Alds[row][seg * 8] =
          *(const int4*)(A + (size_t)(mBase + row) * 512 + k0 + seg * 8);
      *(int4*)&Blds[row][seg * 8] =
          *(const int4*)(Wt + (size_t)(nBase + row) * 512 + k0 + seg * 8);
    }
    __syncthreads();
#pragma unroll
    for (int kk = 0; kk < 64; kk += 32) {
      bf16x8 afr[4], bfr[4];
#pragma unroll
      for (int mi = 0; mi < 4; mi++)
        afr[mi] = *(const bf16x8*)&Alds[wr * 64 + mi * 16 + lr][kk + lg * 8];
#pragma unroll
      for (int ni = 0; ni < 4; ni++)
        bfr[ni] = *(const bf16x8*)&Blds[wc * 64 + ni * 16 + lr][kk + lg * 8];
#pragma unroll
      for (int mi = 0; mi < 4; mi++)
#pragma unroll
        for (int ni = 0; ni < 4; ni++)
          acc[mi][ni] = __builtin_amdgcn_mfma_f32_16x16x32_bf16(
              afr[mi], bfr[ni], acc[mi][ni], 0, 0, 0);
    }
    __syncthreads();
  }

  // epilogue. C/D layout: col = lane&15, row = 4*(lane>>4) + reg  [HW-measured]
#pragma unroll
  for (int mi = 0; mi < 4; mi++) {
#pragma unroll
    for (int ni = 0; ni < 4; ni++) {
#pragma unroll
      for (int rg = 0; rg < 4; rg++) {
        int r = mBase + wr * 64 + mi * 16 + lg * 4 + rg;
        int c = nBase + wc * 64 + ni * 16 + lr;
        float v = acc[mi][ni][rg];
        if (mode < 3) {
          int b = r >> 12, s = r & 4095, h = c >> 6, d = c & 63;
          qkv[(size_t)mode * ((size_t)MTOT * 512) +
              ((((size_t)b * NHEADS + h) * SEQ + s) * DH + d)] = f2b(v);
        } else {
          outF[(size_t)r * 512 + c] = v;
        }
      }
    }
  }
}

// ---------------- flash attention ----------------
// grid (SEQ/64, BATCH*NHEADS), block 256 (4 waves). Wave w owns q-rows
// blockIdx.x*64 + w*16 .. +15. KV blocks of 64 keys.
__global__ __launch_bounds__(256) void attn_kernel(
    const unsigned short* __restrict__ Qb,
    const unsigned short* __restrict__ Kb,
    const unsigned short* __restrict__ Vb,
    unsigned short* __restrict__ CTX) {
  int bh = blockIdx.y;
  int b = bh >> 3, h = bh & 7;
  const unsigned short* Qp = Qb + (size_t)bh * SEQ * DH;
  const unsigned short* Kp = Kb + (size_t)bh * SEQ * DH;
  const unsigned short* Vp = Vb + (size_t)bh * SEQ * DH;

  __shared__ __align__(16) unsigned short Klds[64][72];
  __shared__ __align__(16) unsigned short Vt[64][72];      // Vt[d][key]
  __shared__ __align__(16) unsigned short Plds[4][16][72]; // per wave: [q_local][key]

  int t = threadIdx.x;
  int lane = t & 63, wave = t >> 6;
  int lr = lane & 15, lg = lane >> 4;
  int q0 = blockIdx.x * 64 + wave * 16;

  // Q fragments (A operand): row = lr, k = kk*32 + 8*lg + j (contiguous 16B)
  bf16x8 aq[2];
#pragma unroll
  for (int kk = 0; kk < 2; ++kk)
    aq[kk] = *(const bf16x8*)(Qp + (size_t)(q0 + lr) * DH + kk * 32 + lg * 8);

  f32x4 zero = {0.f, 0.f, 0.f, 0.f};
  f32x4 o[4];
  float m2[4], lsum[4];
#pragma unroll
  for (int dt = 0; dt < 4; dt++) o[dt] = zero;
#pragma unroll
  for (int r = 0; r < 4; r++) { m2[r] = -1e30f; lsum[r] = 0.f; }

  const float c2 = 0.125f * 1.44269504088896340736f;  // 1/sqrt(64) * log2(e)

  int seg = t & 7, r0 = t >> 3;

  for (int kb = 0; kb < SEQ / 64; ++kb) {
    // stage K tile [64 keys][64 d] and transposed V tile Vt[64 d][64 keys]
#pragma unroll
    for (int p = 0; p < 2; ++p) {
      int row = r0 + p * 32;
      *(int4*)&Klds[row][seg * 8] =
          *(const int4*)(Kp + (size_t)(kb * 64 + row) * DH + seg * 8);
      int4 vv = *(const int4*)(Vp + (size_t)(kb * 64 + row) * DH + seg * 8);
      unsigned short* ve = (unsigned short*)&vv;
#pragma unroll
      for (int j = 0; j < 8; ++j) Vt[seg * 8 + j][row] = ve[j];
    }
    __syncthreads();

    // QK^T: S tile 16 q x 64 keys in 4 accumulators
    f32x4 sacc[4];
#pragma unroll
    for (int nt = 0; nt < 4; nt++) {
      sacc[nt] = zero;
#pragma unroll
      for (int kk = 0; kk < 2; kk++) {
        bf16x8 bk = *(const bf16x8*)&Klds[nt * 16 + lr][kk * 32 + lg * 8];
        sacc[nt] = __builtin_amdgcn_mfma_f32_16x16x32_bf16(aq[kk], bk, sacc[nt], 0, 0, 0);
      }
    }

    // online softmax in base-2 domain; lane holds rows q_local = 4*lg + r
    float rm[4];
#pragma unroll
    for (int r = 0; r < 4; r++) {
      float v = sacc[0][r];
      v = fmaxf(v, sacc[1][r]); v = fmaxf(v, sacc[2][r]); v = fmaxf(v, sacc[3][r]);
      v *= c2;
#pragma unroll
      for (int msk = 1; msk < 16; msk <<= 1) v = fmaxf(v, __shfl_xor(v, msk));
      rm[r] = v;
    }
    float corr[4], rs[4];
#pragma unroll
    for (int r = 0; r < 4; r++) {
      float mn = fmaxf(m2[r], rm[r]);
      corr[r] = fexp2(m2[r] - mn);
      m2[r] = mn;
      rs[r] = 0.f;
    }
#pragma unroll
    for (int nt = 0; nt < 4; nt++) {
#pragma unroll
      for (int r = 0; r < 4; r++) {
        float p = fexp2(sacc[nt][r] * c2 - m2[r]);
        rs[r] += p;
        Plds[wave][lg * 4 + r][nt * 16 + lr] = f2b(p);
      }
    }
#pragma unroll
    for (int r = 0; r < 4; r++) {
#pragma unroll
      for (int msk = 1; msk < 16; msk <<= 1) rs[r] += __shfl_xor(rs[r], msk);
      lsum[r] = lsum[r] * corr[r] + rs[r];
    }
#pragma unroll
    for (int dt = 0; dt < 4; dt++) {
      f32x4 tmp = o[dt];
      tmp[0] *= corr[0]; tmp[1] *= corr[1]; tmp[2] *= corr[2]; tmp[3] *= corr[3];
      o[dt] = tmp;
    }
    __syncthreads();  // order P writes before cross-lane P reads

    // PV: A = P (16 q x 64 keys), B = Vt
    bf16x8 ap[2];
#pragma unroll
    for (int ks = 0; ks < 2; ks++)
      ap[ks] = *(const bf16x8*)&Plds[wave][lr][ks * 32 + lg * 8];
#pragma unroll
    for (int dt = 0; dt < 4; dt++) {
#pragma unroll
      for (int ks = 0; ks < 2; ks++) {
        bf16x8 bv = *(const bf16x8*)&Vt[dt * 16 + lr][ks * 32 + lg * 8];
        o[dt] = __builtin_amdgcn_mfma_f32_16x16x32_bf16(ap[ks], bv, o[dt], 0, 0, 0);
      }
    }
    __syncthreads();  // protect K/Vt/P before next iteration's staging
  }

  // epilogue: divide by row sums, write context [B,S,H*Dh] bf16
#pragma unroll
  for (int r = 0; r < 4; r++) lsum[r] = 1.f / lsum[r];
#pragma unroll
  for (int dt = 0; dt < 4; dt++) {
#pragma unroll
    for (int r = 0; r < 4; r++) {
      int qrow = q0 + lg * 4 + r;
      int col = h * 64 + dt * 16 + lr;
      float v = o[dt][r] * lsum[r];
      CTX[((size_t)(b * SEQ + qrow)) * 512 + col] = f2b(v);
    }
  }
}

// ---------------- launch ----------------

extern "C" void kernel_launch(void* const* d_in, const int* in_sizes, int n_in,
                              void* d_out, int out_size, void* d_ws, size_t ws_size,
                              hipStream_t stream) {
  const float* X  = (const float*)d_in[0];
  const float* Wq = (const float*)d_in[1];
  const float* Wk = (const float*)d_in[2];
  const float* Wv = (const float*)d_in[3];
  const float* Wo = (const float*)d_in[4];
  float* out = (float*)d_out;

  char* ws = (char*)d_ws;
  // ws layout (bytes): 4 transposed bf16 weights (4*512KB), Xb (8MB),
  // Q/K/V (3*8MB), CTX (8MB) -> ~42MB total
  unsigned short* Wqt = (unsigned short*)(ws);
  unsigned short* Wot = (unsigned short*)(ws + 3u * 524288u);
  unsigned short* Xb  = (unsigned short*)(ws + 4u * 524288u);
  unsigned short* Qb  = (unsigned short*)(ws + 4u * 524288u + 8388608u);
  unsigned short* Kb  = Qb + (size_t)MTOT * 512;
  unsigned short* Vb  = Kb + (size_t)MTOT * 512;
  unsigned short* CTX = Vb + (size_t)MTOT * 512;

  int nX = MTOT * D_MODEL;  // 4194304
  cvt_x_kernel<<<dim3(nX / (8 * 256)), dim3(256), 0, stream>>>(X, Xb, nX);
  cvt_w_kernel<<<dim3(1024, 4), dim3(256), 0, stream>>>(Wq, Wk, Wv, Wo, Wqt);
  gemm128_kernel<<<dim3(64, 4, 3), dim3(256), 0, stream>>>(Xb, Wqt, Qb, nullptr, -1);
  attn_kernel<<<dim3(SEQ / 64, BATCH * NHEADS), dim3(256), 0, stream>>>(Qb, Kb, Vb, CTX);
  gemm128_kernel<<<dim3(64, 4, 1), dim3(256), 0, stream>>>(CTX, Wot, nullptr, out, 3);
}

// Round 6
// 305.862 us; speedup vs baseline: 1.2606x; 1.2606x over previous
//
#include <hip/hip_runtime.h>

#define D_MODEL 512
#define NHEADS 8
#define DH 64
#define BATCH 2
#define SEQ 4096
#define MTOT (BATCH*SEQ)   // 8192

typedef __attribute__((ext_vector_type(8))) short bf16x8;
typedef __attribute__((ext_vector_type(4))) float f32x4;

__device__ __forceinline__ unsigned short f2b(float f) {
  unsigned int u = __float_as_uint(f);
  u = (u + 0x7fffu + ((u >> 16) & 1u)) >> 16;
  return (unsigned short)u;
}

__device__ __forceinline__ float fexp2(float x) {
  return __builtin_amdgcn_exp2f(x);   // v_exp_f32 (input already base-2)
}

// ---------------- conversion kernels ----------------

__global__ void cvt_x_kernel(const float* __restrict__ X,
                             unsigned short* __restrict__ Xb, int n) {
  int i = (blockIdx.x * blockDim.x + threadIdx.x) * 8;
  if (i >= n) return;
  const float4* s = (const float4*)(X + i);
  float4 v0 = s[0], v1 = s[1];
  union { bf16x8 v; unsigned short u[8]; } r;
  r.u[0] = f2b(v0.x); r.u[1] = f2b(v0.y); r.u[2] = f2b(v0.z); r.u[3] = f2b(v0.w);
  r.u[4] = f2b(v1.x); r.u[5] = f2b(v1.y); r.u[6] = f2b(v1.z); r.u[7] = f2b(v1.w);
  *(bf16x8*)(Xb + i) = r.v;
}

// W is [in=k][out=n] (512x512). Write Wt[n][k] bf16 so B-fragments read contiguous k.
__global__ void cvt_w_kernel(const float* __restrict__ W0, const float* __restrict__ W1,
                             const float* __restrict__ W2, const float* __restrict__ W3,
                             unsigned short* __restrict__ Wt) {
  const float* Ws[4] = {W0, W1, W2, W3};
  const float* W = Ws[blockIdx.y];
  int t = blockIdx.x * blockDim.x + threadIdx.x;   // 0..262143
  int k = t >> 9, n = t & 511;
  Wt[(size_t)blockIdx.y * (512*512) + (size_t)n * 512 + k] = f2b(W[t]);
}

// ---------------- 128x128 bf16 MFMA GEMM ----------------
__global__ __launch_bounds__(256) void gemm128_kernel(
    const unsigned short* __restrict__ A,
    const unsigned short* __restrict__ WtAll,
    unsigned short* __restrict__ qkv,
    float* __restrict__ outF,
    int modeParam) {
  int mode = (modeParam < 0) ? (int)blockIdx.z : modeParam;
  const unsigned short* Wt = WtAll + (size_t)((modeParam < 0) ? blockIdx.z : 0) * (512*512);

  __shared__ __align__(16) unsigned short Alds[128][72];
  __shared__ __align__(16) unsigned short Blds[128][72];

  int t = threadIdx.x;
  int lane = t & 63, wave = t >> 6;
  int wr = wave >> 1, wc = wave & 1;
  int lr = lane & 15, lg = lane >> 4;
  int mBase = blockIdx.x * 128;
  int nBase = blockIdx.y * 128;

  f32x4 zero = {0.f, 0.f, 0.f, 0.f};
  f32x4 acc[4][4];
#pragma unroll
  for (int i = 0; i < 4; i++)
#pragma unroll
    for (int j = 0; j < 4; j++) acc[i][j] = zero;

  int seg = t & 7, r0 = t >> 3;

  for (int k0 = 0; k0 < 512; k0 += 64) {
#pragma unroll
    for (int p = 0; p < 4; ++p) {
      int row = r0 + p * 32;
      *(int4*)&Alds[row][seg * 8] =
          *(const int4*)(A + (size_t)(mBase + row) * 512 + k0 + seg * 8);
      *(int4*)&Blds[row][seg * 8] =
          *(const int4*)(Wt + (size_t)(nBase + row) * 512 + k0 + seg * 8);
    }
    __syncthreads();
#pragma unroll
    for (int kk = 0; kk < 64; kk += 32) {
      bf16x8 afr[4], bfr[4];
#pragma unroll
      for (int mi = 0; mi < 4; mi++)
        afr[mi] = *(const bf16x8*)&Alds[wr * 64 + mi * 16 + lr][kk + lg * 8];
#pragma unroll
      for (int ni = 0; ni < 4; ni++)
        bfr[ni] = *(const bf16x8*)&Blds[wc * 64 + ni * 16 + lr][kk + lg * 8];
#pragma unroll
      for (int mi = 0; mi < 4; mi++)
#pragma unroll
        for (int ni = 0; ni < 4; ni++)
          acc[mi][ni] = __builtin_amdgcn_mfma_f32_16x16x32_bf16(
              afr[mi], bfr[ni], acc[mi][ni], 0, 0, 0);
    }
    __syncthreads();
  }

  // epilogue. C/D layout: col = lane&15, row = 4*(lane>>4) + reg  [HW-measured]
#pragma unroll
  for (int mi = 0; mi < 4; mi++) {
#pragma unroll
    for (int ni = 0; ni < 4; ni++) {
#pragma unroll
      for (int rg = 0; rg < 4; rg++) {
        int r = mBase + wr * 64 + mi * 16 + lg * 4 + rg;
        int c = nBase + wc * 64 + ni * 16 + lr;
        float v = acc[mi][ni][rg];
        if (mode < 3) {
          int b = r >> 12, s = r & 4095, h = c >> 6, d = c & 63;
          qkv[(size_t)mode * ((size_t)MTOT * 512) +
              ((((size_t)b * NHEADS + h) * SEQ + s) * DH + d)] = f2b(v);
        } else {
          outF[(size_t)r * 512 + c] = v;
        }
      }
    }
  }
}

// ---------------- flash attention ----------------
// grid (SEQ/64, BATCH*NHEADS), block 256 (4 waves). Wave w owns q-rows
// blockIdx.x*64 + w*16 .. +15. KV blocks of 64 keys.
//
// VtS layout (XOR block-swizzle to kill transpose-write bank conflicts):
// element (d, key) lives at VtS[d][ ((key>>3) ^ (d>>3)) * 8 + (key&7) ].
// Writes: bank = 4j + 4*(blk^seg) + (key&7)>>1 covers all 32 banks (2 lanes
// share a dword = free). PV b128 reads land exactly 8 lanes per 4-bank group
// = the b128 floor -> conflict-free.
__global__ __launch_bounds__(256) void attn_kernel(
    const unsigned short* __restrict__ Qb,
    const unsigned short* __restrict__ Kb,
    const unsigned short* __restrict__ Vb,
    unsigned short* __restrict__ CTX) {
  int bh = blockIdx.y;
  int b = bh >> 3, h = bh & 7;
  const unsigned short* Qp = Qb + (size_t)bh * SEQ * DH;
  const unsigned short* Kp = Kb + (size_t)bh * SEQ * DH;
  const unsigned short* Vp = Vb + (size_t)bh * SEQ * DH;

  __shared__ __align__(16) unsigned short Klds[64][72];
  __shared__ __align__(16) unsigned short VtS[64][72];     // swizzled V^T
  __shared__ __align__(16) unsigned short Plds[4][16][72]; // per wave: [q_local][key]

  int t = threadIdx.x;
  int lane = t & 63, wave = t >> 6;
  int lr = lane & 15, lg = lane >> 4;
  int q0 = blockIdx.x * 64 + wave * 16;

  // Q fragments (A operand): row = lr, k = kk*32 + 8*lg + j (contiguous 16B)
  bf16x8 aq[2];
#pragma unroll
  for (int kk = 0; kk < 2; ++kk)
    aq[kk] = *(const bf16x8*)(Qp + (size_t)(q0 + lr) * DH + kk * 32 + lg * 8);

  f32x4 zero = {0.f, 0.f, 0.f, 0.f};
  f32x4 o[4];
  float m2[4], lsum[4];
#pragma unroll
  for (int dt = 0; dt < 4; dt++) o[dt] = zero;
#pragma unroll
  for (int r = 0; r < 4; r++) { m2[r] = -1e30f; lsum[r] = 0.f; }

  const float c2 = 0.125f * 1.44269504088896340736f;  // 1/sqrt(64) * log2(e)

  int seg = t & 7, r0 = t >> 3;   // staging coords: seg = 16B segment, r0 = row
  const int NT = SEQ / 64;

  // T14 async-stage: preload tile 0 into registers
  int4 kreg[2], vreg[2];
#pragma unroll
  for (int p = 0; p < 2; ++p) {
    int row = r0 + p * 32;
    kreg[p] = *(const int4*)(Kp + (size_t)row * DH + seg * 8);
    vreg[p] = *(const int4*)(Vp + (size_t)row * DH + seg * 8);
  }

  for (int kb = 0; kb < NT; ++kb) {
    // write staged registers -> LDS (K row-major, V transposed+swizzled)
#pragma unroll
    for (int p = 0; p < 2; ++p) {
      int row = r0 + p * 32;
      *(int4*)&Klds[row][seg * 8] = kreg[p];
      unsigned short* ve = (unsigned short*)&vreg[p];
      int blk = row >> 3, within = row & 7;
#pragma unroll
      for (int j = 0; j < 8; ++j)
        VtS[seg * 8 + j][(((blk ^ seg) << 3) | within)] = ve[j];
    }
    __syncthreads();

    // issue next tile's global loads (latency hides under QK/softmax/PV)
    if (kb + 1 < NT) {
#pragma unroll
      for (int p = 0; p < 2; ++p) {
        int row = r0 + p * 32;
        kreg[p] = *(const int4*)(Kp + (size_t)((kb + 1) * 64 + row) * DH + seg * 8);
        vreg[p] = *(const int4*)(Vp + (size_t)((kb + 1) * 64 + row) * DH + seg * 8);
      }
    }

    // QK^T: S tile 16 q x 64 keys in 4 accumulators
    f32x4 sacc[4];
#pragma unroll
    for (int nt = 0; nt < 4; nt++) {
      sacc[nt] = zero;
#pragma unroll
      for (int kk = 0; kk < 2; kk++) {
        bf16x8 bk = *(const bf16x8*)&Klds[nt * 16 + lr][kk * 32 + lg * 8];
        sacc[nt] = __builtin_amdgcn_mfma_f32_16x16x32_bf16(aq[kk], bk, sacc[nt], 0, 0, 0);
      }
    }

    // online softmax in base-2 domain; lane holds rows q_local = 4*lg + r
    float rm[4];
#pragma unroll
    for (int r = 0; r < 4; r++) {
      float v = sacc[0][r];
      v = fmaxf(v, sacc[1][r]); v = fmaxf(v, sacc[2][r]); v = fmaxf(v, sacc[3][r]);
      v *= c2;
#pragma unroll
      for (int msk = 1; msk < 16; msk <<= 1) v = fmaxf(v, __shfl_xor(v, msk));
      rm[r] = v;
    }
    float corr[4], rs[4];
#pragma unroll
    for (int r = 0; r < 4; r++) {
      float mn = fmaxf(m2[r], rm[r]);
      corr[r] = fexp2(m2[r] - mn);
      m2[r] = mn;
      rs[r] = 0.f;
    }
#pragma unroll
    for (int nt = 0; nt < 4; nt++) {
#pragma unroll
      for (int r = 0; r < 4; r++) {
        float p = fexp2(sacc[nt][r] * c2 - m2[r]);
        rs[r] += p;
        Plds[wave][lg * 4 + r][nt * 16 + lr] = f2b(p);
      }
    }
#pragma unroll
    for (int r = 0; r < 4; r++) {
#pragma unroll
      for (int msk = 1; msk < 16; msk <<= 1) rs[r] += __shfl_xor(rs[r], msk);
      lsum[r] = lsum[r] * corr[r] + rs[r];
    }
#pragma unroll
    for (int dt = 0; dt < 4; dt++) {
      f32x4 tmp = o[dt];
      tmp[0] *= corr[0]; tmp[1] *= corr[1]; tmp[2] *= corr[2]; tmp[3] *= corr[3];
      o[dt] = tmp;
    }
    __syncthreads();  // order P writes before cross-lane P reads

    // PV: A = P (16 q x 64 keys), B = VtS (swizzled)
    bf16x8 ap[2];
#pragma unroll
    for (int ks = 0; ks < 2; ks++)
      ap[ks] = *(const bf16x8*)&Plds[wave][lr][ks * 32 + lg * 8];
#pragma unroll
    for (int dt = 0; dt < 4; dt++) {
      int d = dt * 16 + lr;
      int segd = (d >> 3) & 7;
#pragma unroll
      for (int ks = 0; ks < 2; ks++) {
        bf16x8 bv = *(const bf16x8*)&VtS[d][((ks * 4 + lg) ^ segd) << 3];
        o[dt] = __builtin_amdgcn_mfma_f32_16x16x32_bf16(ap[ks], bv, o[dt], 0, 0, 0);
      }
    }
    __syncthreads();  // protect Klds/VtS/Plds before next iteration's writes
  }

  // epilogue: divide by row sums, write context [B,S,H*Dh] bf16
#pragma unroll
  for (int r = 0; r < 4; r++) lsum[r] = 1.f / lsum[r];
#pragma unroll
  for (int dt = 0; dt < 4; dt++) {
#pragma unroll
    for (int r = 0; r < 4; r++) {
      int qrow = q0 + lg * 4 + r;
      int col = h * 64 + dt * 16 + lr;
      float v = o[dt][r] * lsum[r];
      CTX[((size_t)(b * SEQ + qrow)) * 512 + col] = f2b(v);
    }
  }
}

// ---------------- launch ----------------

extern "C" void kernel_launch(void* const* d_in, const int* in_sizes, int n_in,
                              void* d_out, int out_size, void* d_ws, size_t ws_size,
                              hipStream_t stream) {
  const float* X  = (const float*)d_in[0];
  const float* Wq = (const float*)d_in[1];
  const float* Wk = (const float*)d_in[2];
  const float* Wv = (const float*)d_in[3];
  const float* Wo = (const float*)d_in[4];
  float* out = (float*)d_out;

  char* ws = (char*)d_ws;
  unsigned short* Wqt = (unsigned short*)(ws);
  unsigned short* Wot = (unsigned short*)(ws + 3u * 524288u);
  unsigned short* Xb  = (unsigned short*)(ws + 4u * 524288u);
  unsigned short* Qb  = (unsigned short*)(ws + 4u * 524288u + 8388608u);
  unsigned short* Kb  = Qb + (size_t)MTOT * 512;
  unsigned short* Vb  = Kb + (size_t)MTOT * 512;
  unsigned short* CTX = Vb + (size_t)MTOT * 512;

  int nX = MTOT * D_MODEL;  // 4194304
  cvt_x_kernel<<<dim3(nX / (8 * 256)), dim3(256), 0, stream>>>(X, Xb, nX);
  cvt_w_kernel<<<dim3(1024, 4), dim3(256), 0, stream>>>(Wq, Wk, Wv, Wo, Wqt);
  gemm128_kernel<<<dim3(64, 4, 3), dim3(256), 0, stream>>>(Xb, Wqt, Qb, nullptr, -1);
  attn_kernel<<<dim3(SEQ / 64, BATCH * NHEADS), dim3(256), 0, stream>>>(Qb, Kb, Vb, CTX);
  gemm128_kernel<<<dim3(64, 4, 1), dim3(256), 0, stream>>>(CTX, Wot, nullptr, out, 3);
}

// Round 8
// 237.662 us; speedup vs baseline: 1.6224x; 1.2870x over previous
//
#include <hip/hip_runtime.h>

#define D_MODEL 512
#define NHEADS 8
#define DH 64
#define BATCH 2
#define SEQ 4096
#define MTOT (BATCH*SEQ)   // 8192

typedef __attribute__((ext_vector_type(8))) short bf16x8;
typedef __attribute__((ext_vector_type(4))) float f32x4;

__device__ __forceinline__ unsigned short f2b(float f) {
  unsigned int u = __float_as_uint(f);
  u = (u + 0x7fffu + ((u >> 16) & 1u)) >> 16;
  return (unsigned short)u;
}

__device__ __forceinline__ float fexp2(float x) {
  return __builtin_amdgcn_exp2f(x);   // v_exp_f32 (input already base-2)
}

// pack 2 f32 -> 2 bf16 in one u32 (lo = a, hi = b)
__device__ __forceinline__ unsigned int cvtpk_bf16(float a, float b) {
  unsigned int r;
  asm("v_cvt_pk_bf16_f32 %0, %1, %2" : "=v"(r) : "v"(a), "v"(b));
  return r;
}

// ---------------- conversion kernels ----------------

__global__ void cvt_x_kernel(const float* __restrict__ X,
                             unsigned short* __restrict__ Xb, int n) {
  int i = (blockIdx.x * blockDim.x + threadIdx.x) * 8;
  if (i >= n) return;
  const float4* s = (const float4*)(X + i);
  float4 v0 = s[0], v1 = s[1];
  union { bf16x8 v; unsigned short u[8]; } r;
  r.u[0] = f2b(v0.x); r.u[1] = f2b(v0.y); r.u[2] = f2b(v0.z); r.u[3] = f2b(v0.w);
  r.u[4] = f2b(v1.x); r.u[5] = f2b(v1.y); r.u[6] = f2b(v1.z); r.u[7] = f2b(v1.w);
  *(bf16x8*)(Xb + i) = r.v;
}

// W is [in=k][out=n] (512x512). Write Wt[n][k] bf16 so B-fragments read contiguous k.
__global__ void cvt_w_kernel(const float* __restrict__ W0, const float* __restrict__ W1,
                             const float* __restrict__ W2, const float* __restrict__ W3,
                             unsigned short* __restrict__ Wt) {
  const float* Ws[4] = {W0, W1, W2, W3};
  const float* W = Ws[blockIdx.y];
  int t = blockIdx.x * blockDim.x + threadIdx.x;   // 0..262143
  int k = t >> 9, n = t & 511;
  Wt[(size_t)blockIdx.y * (512*512) + (size_t)n * 512 + k] = f2b(W[t]);
}

// ---------------- 128x128 bf16 MFMA GEMM ----------------
__global__ __launch_bounds__(256) void gemm128_kernel(
    const unsigned short* __restrict__ A,
    const unsigned short* __restrict__ WtAll,
    unsigned short* __restrict__ qkv,
    float* __restrict__ outF,
    int modeParam) {
  int mode = (modeParam < 0) ? (int)blockIdx.z : modeParam;
  const unsigned short* Wt = WtAll + (size_t)((modeParam < 0) ? blockIdx.z : 0) * (512*512);

  __shared__ __align__(16) unsigned short Alds[128][72];
  __shared__ __align__(16) unsigned short Blds[128][72];

  int t = threadIdx.x;
  int lane = t & 63, wave = t >> 6;
  int wr = wave >> 1, wc = wave & 1;
  int lr = lane & 15, lg = lane >> 4;
  int mBase = blockIdx.x * 128;
  int nBase = blockIdx.y * 128;

  f32x4 zero = {0.f, 0.f, 0.f, 0.f};
  f32x4 acc[4][4];
#pragma unroll
  for (int i = 0; i < 4; i++)
#pragma unroll
    for (int j = 0; j < 4; j++) acc[i][j] = zero;

  int seg = t & 7, r0 = t >> 3;

  for (int k0 = 0; k0 < 512; k0 += 64) {
#pragma unroll
    for (int p = 0; p < 4; ++p) {
      int row = r0 + p * 32;
      *(int4*)&Alds[row][seg * 8] =
          *(const int4*)(A + (size_t)(mBase + row) * 512 + k0 + seg * 8);
      *(int4*)&Blds[row][seg * 8] =
          *(const int4*)(Wt + (size_t)(nBase + row) * 512 + k0 + seg * 8);
    }
    __syncthreads();
#pragma unroll
    for (int kk = 0; kk < 64; kk += 32) {
      bf16x8 afr[4], bfr[4];
#pragma unroll
      for (int mi = 0; mi < 4; mi++)
        afr[mi] = *(const bf16x8*)&Alds[wr * 64 + mi * 16 + lr][kk + lg * 8];
#pragma unroll
      for (int ni = 0; ni < 4; ni++)
        bfr[ni] = *(const bf16x8*)&Blds[wc * 64 + ni * 16 + lr][kk + lg * 8];
#pragma unroll
      for (int mi = 0; mi < 4; mi++)
#pragma unroll
        for (int ni = 0; ni < 4; ni++)
          acc[mi][ni] = __builtin_amdgcn_mfma_f32_16x16x32_bf16(
              afr[mi], bfr[ni], acc[mi][ni], 0, 0, 0);
    }
    __syncthreads();
  }

  // epilogue. C/D layout: col = lane&15, row = 4*(lane>>4) + reg  [HW-measured]
#pragma unroll
  for (int mi = 0; mi < 4; mi++) {
#pragma unroll
    for (int ni = 0; ni < 4; ni++) {
#pragma unroll
      for (int rg = 0; rg < 4; rg++) {
        int r = mBase + wr * 64 + mi * 16 + lg * 4 + rg;
        int c = nBase + wc * 64 + ni * 16 + lr;
        float v = acc[mi][ni][rg];
        if (mode < 3) {
          int b = r >> 12, s = r & 4095, h = c >> 6, d = c & 63;
          qkv[(size_t)mode * ((size_t)MTOT * 512) +
              ((((size_t)b * NHEADS + h) * SEQ + s) * DH + d)] = f2b(v);
        } else {
          outF[(size_t)r * 512 + c] = v;
        }
      }
    }
  }
}

// ---------------- flash attention (swapped-QK, lane-local softmax) ----------------
// grid (SEQ/64, BATCH*NHEADS), block 256 (4 waves). Wave w owns q-rows
// blockIdx.x*64 + w*16 .. +15 (q = lane&15 within the wave). KV blocks of 64.
//
// QK^T computed swapped: S^T = mfma(A=K, B=Q) -> lane holds S[key=16nt+4lg+r][q=lr]:
// softmax over keys is lane-local (16 vals) + 2 shfl_xor across the 4 lg groups.
// P packed to bf16 via v_cvt_pk_bf16_f32 into per-wave PT[q][key]; b128 readback
// is exactly the PV B-fragment. PT is per-wave -> intra-wave in-order LDS, no
// barrier. PV: O^T = mfma(A=V^T, B=P^T). Epilogue transposes O via PT buffer
// for coalesced global writes.
__global__ __launch_bounds__(256) void attn_kernel(
    const unsigned short* __restrict__ Qb,
    const unsigned short* __restrict__ Kb,
    const unsigned short* __restrict__ Vb,
    unsigned short* __restrict__ CTX) {
  int bh = blockIdx.y;
  int b = bh >> 3, h = bh & 7;
  const unsigned short* Qp = Qb + (size_t)bh * SEQ * DH;
  const unsigned short* Kp = Kb + (size_t)bh * SEQ * DH;
  const unsigned short* Vp = Vb + (size_t)bh * SEQ * DH;

  __shared__ __align__(16) unsigned short Klds[64][72];
  __shared__ __align__(16) unsigned short VtS[64][72];    // swizzled V^T
  __shared__ __align__(16) unsigned short PT[4][16][72];  // per wave: P[q][key]

  int t = threadIdx.x;
  int lane = t & 63, wave = t >> 6;
  int lr = lane & 15, lg = lane >> 4;
  int q0 = blockIdx.x * 64 + wave * 16;

  // Q fragments (B operand): col=q=lr, k = kk*32 + 8*lg + j (contiguous 16B)
  bf16x8 aq[2];
#pragma unroll
  for (int kk = 0; kk < 2; ++kk)
    aq[kk] = *(const bf16x8*)(Qp + (size_t)(q0 + lr) * DH + kk * 32 + lg * 8);

  f32x4 zero = {0.f, 0.f, 0.f, 0.f};
  f32x4 o[4];   // O^T: lane holds O[q=lr][d = dt*16 + 4*lg + r]
#pragma unroll
  for (int dt = 0; dt < 4; dt++) o[dt] = zero;
  float m2 = -1e30f, lsum = 0.f;   // per-lane scalars (q = lr)

  const float c2 = 0.125f * 1.44269504088896340736f;  // 1/sqrt(64) * log2(e)

  int seg = t & 7, r0 = t >> 3;   // staging coords
  const int NT = SEQ / 64;

  // T14 async-stage: preload tile 0 into registers
  int4 kreg[2], vreg[2];
#pragma unroll
  for (int p = 0; p < 2; ++p) {
    int row = r0 + p * 32;
    kreg[p] = *(const int4*)(Kp + (size_t)row * DH + seg * 8);
    vreg[p] = *(const int4*)(Vp + (size_t)row * DH + seg * 8);
  }

  for (int kb = 0; kb < NT; ++kb) {
    // staged regs -> LDS (K row-major, V transposed+XOR-swizzled)
#pragma unroll
    for (int p = 0; p < 2; ++p) {
      int row = r0 + p * 32;
      *(int4*)&Klds[row][seg * 8] = kreg[p];
      unsigned short* ve = (unsigned short*)&vreg[p];
      int blk = row >> 3, within = row & 7;
#pragma unroll
      for (int j = 0; j < 8; ++j)
        VtS[seg * 8 + j][(((blk ^ seg) << 3) | within)] = ve[j];
    }
    __syncthreads();

    // issue next tile's global loads (latency hides under compute)
    if (kb + 1 < NT) {
#pragma unroll
      for (int p = 0; p < 2; ++p) {
        int row = r0 + p * 32;
        kreg[p] = *(const int4*)(Kp + (size_t)((kb + 1) * 64 + row) * DH + seg * 8);
        vreg[p] = *(const int4*)(Vp + (size_t)((kb + 1) * 64 + row) * DH + seg * 8);
      }
    }

    // QK^T swapped: sacc[nt][r] = S[key = nt*16 + 4*lg + r][q = lr]
    f32x4 sacc[4];
#pragma unroll
    for (int nt = 0; nt < 4; nt++) {
      sacc[nt] = zero;
#pragma unroll
      for (int kk = 0; kk < 2; kk++) {
        bf16x8 bk = *(const bf16x8*)&Klds[nt * 16 + lr][kk * 32 + lg * 8];
        sacc[nt] = __builtin_amdgcn_mfma_f32_16x16x32_bf16(bk, aq[kk], sacc[nt], 0, 0, 0);
      }
    }

    // lane-local softmax (base-2)
    float pm;
    {
      float a0 = fmaxf(fmaxf(sacc[0][0], sacc[0][1]), fmaxf(sacc[0][2], sacc[0][3]));
      float a1 = fmaxf(fmaxf(sacc[1][0], sacc[1][1]), fmaxf(sacc[1][2], sacc[1][3]));
      float a2 = fmaxf(fmaxf(sacc[2][0], sacc[2][1]), fmaxf(sacc[2][2], sacc[2][3]));
      float a3 = fmaxf(fmaxf(sacc[3][0], sacc[3][1]), fmaxf(sacc[3][2], sacc[3][3]));
      pm = fmaxf(fmaxf(a0, a1), fmaxf(a2, a3)) * c2;
    }
    pm = fmaxf(pm, __shfl_xor(pm, 16));
    pm = fmaxf(pm, __shfl_xor(pm, 32));

    // T13 defer-max: only rescale when the max moved by > 8 (base-2)
    if (!__all((int)(pm <= m2 + 8.f))) {
      float mn = fmaxf(m2, pm);
      float corr = fexp2(m2 - mn);
      m2 = mn;
      lsum *= corr;
#pragma unroll
      for (int dt = 0; dt < 4; dt++) {
        f32x4 tmp = o[dt];
        tmp[0] *= corr; tmp[1] *= corr; tmp[2] *= corr; tmp[3] *= corr;
        o[dt] = tmp;
      }
    }

    float p[4][4];
    float rs = 0.f;
#pragma unroll
    for (int nt = 0; nt < 4; nt++)
#pragma unroll
      for (int r = 0; r < 4; r++) {
        float v = fexp2(fmaf(sacc[nt][r], c2, -m2));
        p[nt][r] = v;
        rs += v;
      }
    rs += __shfl_xor(rs, 16);
    rs += __shfl_xor(rs, 32);
    lsum += rs;

    // pack P -> PT[q][key] (per-wave; intra-wave in-order LDS, no barrier)
#pragma unroll
    for (int nt = 0; nt < 4; nt++)
#pragma unroll
      for (int c = 0; c < 2; c++)
        *(unsigned int*)&PT[wave][lr][nt * 16 + lg * 4 + 2 * c] =
            cvtpk_bf16(p[nt][2 * c], p[nt][2 * c + 1]);

    // PV: O^T += V^T * P^T
    bf16x8 ap[2];
#pragma unroll
    for (int ks = 0; ks < 2; ks++)
      ap[ks] = *(const bf16x8*)&PT[wave][lr][ks * 32 + lg * 8];
#pragma unroll
    for (int dt = 0; dt < 4; dt++) {
      int d = dt * 16 + lr;
      int segd = (d >> 3) & 7;
#pragma unroll
      for (int ks = 0; ks < 2; ks++) {
        bf16x8 bv = *(const bf16x8*)&VtS[d][((ks * 4 + lg) ^ segd) << 3];
        o[dt] = __builtin_amdgcn_mfma_f32_16x16x32_bf16(bv, ap[ks], o[dt], 0, 0, 0);
      }
    }
    __syncthreads();  // protect Klds/VtS before next iteration's staging
  }

  // epilogue: normalize, transpose O through PT buffer, coalesced global write
  float inv = 1.f / lsum;
#pragma unroll
  for (int dt = 0; dt < 4; dt++)
#pragma unroll
    for (int c = 0; c < 2; c++)
      *(unsigned int*)&PT[wave][lr][dt * 16 + lg * 4 + 2 * c] =
          cvtpk_bf16(o[dt][2 * c] * inv, o[dt][2 * c + 1] * inv);

  int row = lane >> 2, cs = lane & 3;
  bf16x8 w0 = *(const bf16x8*)&PT[wave][row][cs * 16];
  bf16x8 w1 = *(const bf16x8*)&PT[wave][row][cs * 16 + 8];
  size_t base = ((size_t)(b * SEQ + q0 + row)) * 512 + h * 64 + cs * 16;
  *(bf16x8*)(CTX + base) = w0;
  *(bf16x8*)(CTX + base + 8) = w1;
}

// ---------------- launch ----------------

extern "C" void kernel_launch(void* const* d_in, const int* in_sizes, int n_in,
                              void* d_out, int out_size, void* d_ws, size_t ws_size,
                              hipStream_t stream) {
  const float* X  = (const float*)d_in[0];
  const float* Wq = (const float*)d_in[1];
  const float* Wk = (const float*)d_in[2];
  const float* Wv = (const float*)d_in[3];
  const float* Wo = (const float*)d_in[4];
  float* out = (float*)d_out;

  char* ws = (char*)d_ws;
  unsigned short* Wqt = (unsigned short*)(ws);
  unsigned short* Wot = (unsigned short*)(ws + 3u * 524288u);
  unsigned short* Xb  = (unsigned short*)(ws + 4u * 524288u);
  unsigned short* Qb  = (unsigned short*)(ws + 4u * 524288u + 8388608u);
  unsigned short* Kb  = Qb + (size_t)MTOT * 512;
  unsigned short* Vb  = Kb + (size_t)MTOT * 512;
  unsigned short* CTX = Vb + (size_t)MTOT * 512;

  int nX = MTOT * D_MODEL;  // 4194304
  cvt_x_kernel<<<dim3(nX / (8 * 256)), dim3(256), 0, stream>>>(X, Xb, nX);
  cvt_w_kernel<<<dim3(1024, 4), dim3(256), 0, stream>>>(Wq, Wk, Wv, Wo, Wqt);
  gemm128_kernel<<<dim3(64, 4, 3), dim3(256), 0, stream>>>(Xb, Wqt, Qb, nullptr, -1);
  attn_kernel<<<dim3(SEQ / 64, BATCH * NHEADS), dim3(256), 0, stream>>>(Qb, Kb, Vb, CTX);
  gemm128_kernel<<<dim3(64, 4, 1), dim3(256), 0, stream>>>(CTX, Wot, nullptr, out, 3);
}

// Round 10
// 189.226 us; speedup vs baseline: 2.0377x; 1.2560x over previous
//
#include <hip/hip_runtime.h>

#define D_MODEL 512
#define NHEADS 8
#define DH 64
#define BATCH 2
#define SEQ 4096
#define MTOT (BATCH*SEQ)   // 8192

typedef __attribute__((ext_vector_type(8))) short bf16x8;
typedef __attribute__((ext_vector_type(4))) short s16x4;
typedef __attribute__((ext_vector_type(4))) float f32x4;

__device__ __forceinline__ unsigned short f2b(float f) {
  unsigned int u = __float_as_uint(f);
  u = (u + 0x7fffu + ((u >> 16) & 1u)) >> 16;
  return (unsigned short)u;
}

__device__ __forceinline__ float fexp2(float x) {
  return __builtin_amdgcn_exp2f(x);
}

// pack 2 f32 -> 2 bf16 in one u32 (lo = a, hi = b)
__device__ __forceinline__ unsigned int cvtpk_bf16(float a, float b) {
  unsigned int r;
  asm("v_cvt_pk_bf16_f32 %0, %1, %2" : "=v"(r) : "v"(a), "v"(b));
  return r;
}

// hardware transpose read. Per-lane semantics (derived from m156/m162):
// tile_base = addr & ~127 (a 4x16 bf16 row-major tile), col = (addr>>3)&15;
// lane receives the 4 bf16 of that COLUMN (rows 0..3).
__device__ __forceinline__ void tr16(unsigned addr, s16x4& d) {
  asm volatile("ds_read_b64_tr_b16 %0, %1" : "=v"(d) : "v"(addr));
}

// ---------------- conversion kernels ----------------

__global__ void cvt_x_kernel(const float* __restrict__ X,
                             unsigned short* __restrict__ Xb, int n) {
  int i = (blockIdx.x * blockDim.x + threadIdx.x) * 8;
  if (i >= n) return;
  const float4* s = (const float4*)(X + i);
  float4 v0 = s[0], v1 = s[1];
  union { bf16x8 v; unsigned short u[8]; } r;
  r.u[0] = f2b(v0.x); r.u[1] = f2b(v0.y); r.u[2] = f2b(v0.z); r.u[3] = f2b(v0.w);
  r.u[4] = f2b(v1.x); r.u[5] = f2b(v1.y); r.u[6] = f2b(v1.z); r.u[7] = f2b(v1.w);
  *(bf16x8*)(Xb + i) = r.v;
}

__global__ void cvt_w_kernel(const float* __restrict__ W0, const float* __restrict__ W1,
                             const float* __restrict__ W2, const float* __restrict__ W3,
                             unsigned short* __restrict__ Wt) {
  const float* Ws[4] = {W0, W1, W2, W3};
  const float* W = Ws[blockIdx.y];
  int t = blockIdx.x * blockDim.x + threadIdx.x;
  int k = t >> 9, n = t & 511;
  Wt[(size_t)blockIdx.y * (512*512) + (size_t)n * 512 + k] = f2b(W[t]);
}

// ---------------- 128x128 bf16 MFMA GEMM ----------------
__global__ __launch_bounds__(256) void gemm128_kernel(
    const unsigned short* __restrict__ A,
    const unsigned short* __restrict__ WtAll,
    unsigned short* __restrict__ qkv,
    float* __restrict__ outF,
    int modeParam) {
  int mode = (modeParam < 0) ? (int)blockIdx.z : modeParam;
  const unsigned short* Wt = WtAll + (size_t)((modeParam < 0) ? blockIdx.z : 0) * (512*512);

  __shared__ __align__(16) unsigned short Alds[128][72];
  __shared__ __align__(16) unsigned short Blds[128][72];

  int t = threadIdx.x;
  int lane = t & 63, wave = t >> 6;
  int wr = wave >> 1, wc = wave & 1;
  int lr = lane & 15, lg = lane >> 4;
  int mBase = blockIdx.x * 128;
  int nBase = blockIdx.y * 128;

  f32x4 zero = {0.f, 0.f, 0.f, 0.f};
  f32x4 acc[4][4];
#pragma unroll
  for (int i = 0; i < 4; i++)
#pragma unroll
    for (int j = 0; j < 4; j++) acc[i][j] = zero;

  int seg = t & 7, r0 = t >> 3;

  for (int k0 = 0; k0 < 512; k0 += 64) {
#pragma unroll
    for (int p = 0; p < 4; ++p) {
      int row = r0 + p * 32;
      *(int4*)&Alds[row][seg * 8] =
          *(const int4*)(A + (size_t)(mBase + row) * 512 + k0 + seg * 8);
      *(int4*)&Blds[row][seg * 8] =
          *(const int4*)(Wt + (size_t)(nBase + row) * 512 + k0 + seg * 8);
    }
    __syncthreads();
#pragma unroll
    for (int kk = 0; kk < 64; kk += 32) {
      bf16x8 afr[4], bfr[4];
#pragma unroll
      for (int mi = 0; mi < 4; mi++)
        afr[mi] = *(const bf16x8*)&Alds[wr * 64 + mi * 16 + lr][kk + lg * 8];
#pragma unroll
      for (int ni = 0; ni < 4; ni++)
        bfr[ni] = *(const bf16x8*)&Blds[wc * 64 + ni * 16 + lr][kk + lg * 8];
#pragma unroll
      for (int mi = 0; mi < 4; mi++)
#pragma unroll
        for (int ni = 0; ni < 4; ni++)
          acc[mi][ni] = __builtin_amdgcn_mfma_f32_16x16x32_bf16(
              afr[mi], bfr[ni], acc[mi][ni], 0, 0, 0);
    }
    __syncthreads();
  }

#pragma unroll
  for (int mi = 0; mi < 4; mi++) {
#pragma unroll
    for (int ni = 0; ni < 4; ni++) {
#pragma unroll
      for (int rg = 0; rg < 4; rg++) {
        int r = mBase + wr * 64 + mi * 16 + lg * 4 + rg;
        int c = nBase + wc * 64 + ni * 16 + lr;
        float v = acc[mi][ni][rg];
        if (mode < 3) {
          int b = r >> 12, s = r & 4095, h = c >> 6, d = c & 63;
          qkv[(size_t)mode * ((size_t)MTOT * 512) +
              ((((size_t)b * NHEADS + h) * SEQ + s) * DH + d)] = f2b(v);
        } else {
          outF[(size_t)r * 512 + c] = v;
        }
      }
    }
  }
}

// ---------------- flash attention ----------------
// grid 512 flat, block 512 (8 waves). XCD-swizzled: xcd = flat&7 hosts 2 heads.
// Wave w owns q-rows qc*128 + w*16 .. +15. KV tiles of 64 keys, double-buffered,
// ONE barrier per tile. K row-major [64][72]; V subtiled [kq][4key][16d]
// (subtile (kq,dt) at byte (kq*4+dt)*128) for ds_read_b64_tr_b16.
// Swapped-QK lane-local softmax as r6 (proven).
__global__ __launch_bounds__(512) void attn_kernel(
    const unsigned short* __restrict__ Qb,
    const unsigned short* __restrict__ Kb,
    const unsigned short* __restrict__ Vb,
    unsigned short* __restrict__ CTX) {
  int flat = blockIdx.x;
  int xcd = flat & 7, jj = flat >> 3;
  int bh = xcd + ((jj >> 5) << 3);   // 2 heads per XCD, bijective (512%8==0)
  int qc = jj & 31;
  int b = bh >> 3, h = bh & 7;
  const unsigned short* Qp = Qb + (size_t)bh * SEQ * DH;
  const unsigned short* Kp = Kb + (size_t)bh * SEQ * DH;
  const unsigned short* Vp = Vb + (size_t)bh * SEQ * DH;

  // 128-byte alignment so V subtiles coincide with tr16 HW tile boundaries
  __shared__ __align__(128) unsigned short Kl[2][64][72];   // 18432 B
  __shared__ __align__(128) unsigned short Vl[2][4096];     // 16384 B
  __shared__ __align__(128) unsigned short PT[8][16][72];   // 18432 B

  int t = threadIdx.x;            // 0..511
  int lane = t & 63, wave = t >> 6;
  int lr = lane & 15, lg = lane >> 4;
  int q0 = qc * 128 + wave * 16;

  // Q fragments (B operand): col=q=lr, k = kk*32 + 8*lg + j
  bf16x8 aq[2];
#pragma unroll
  for (int kk = 0; kk < 2; ++kk)
    aq[kk] = *(const bf16x8*)(Qp + (size_t)(q0 + lr) * DH + kk * 32 + lg * 8);

  f32x4 zero = {0.f, 0.f, 0.f, 0.f};
  f32x4 o[4];
#pragma unroll
  for (int dt = 0; dt < 4; dt++) o[dt] = zero;
  float m2 = -1e30f, lsum = 0.f;

  const float c2 = 0.125f * 1.44269504088896340736f;

  // staging coords: 512 threads cover 64 rows x 8 segs of 8 bf16
  int srow = t >> 3, sseg = t & 7;
  // V LDS dest (u16 units): subtile kq=srow>>2, dt=sseg>>1; row srow&3, dofs (sseg&1)*8
  int vdst = ((srow >> 2) * 4 + (sseg >> 1)) * 64 + (srow & 3) * 16 + (sseg & 1) * 8;
  const int NT = SEQ / 64;

  // per-lane tr-read base (bytes): group tile + column SLOT (8 bytes per slot!)
  unsigned vtr_lane = (unsigned)(lg * 1024 + lr * 8);
  unsigned vbuf0 = (unsigned)(size_t)&Vl[0][0];
  unsigned vbuf1 = (unsigned)(size_t)&Vl[1][0];

  // preload tile 0
  int4 kreg = *(const int4*)(Kp + (size_t)srow * DH + sseg * 8);
  int4 vreg = *(const int4*)(Vp + (size_t)srow * DH + sseg * 8);

  for (int kb = 0; kb < NT; ++kb) {
    int cur = kb & 1;
    *(int4*)&Kl[cur][srow][sseg * 8] = kreg;
    *(int4*)&Vl[cur][vdst] = vreg;
    if (kb + 1 < NT) {
      kreg = *(const int4*)(Kp + (size_t)((kb + 1) * 64 + srow) * DH + sseg * 8);
      vreg = *(const int4*)(Vp + (size_t)((kb + 1) * 64 + srow) * DH + sseg * 8);
    }
    __syncthreads();   // buf[cur] ready; kb-2 readers proven past barrier(kb-1)

    // QK^T swapped: sacc[nt][r] = S[key = nt*16 + 4*lg + r][q = lr]
    f32x4 sacc[4];
#pragma unroll
    for (int nt = 0; nt < 4; nt++) {
      sacc[nt] = zero;
#pragma unroll
      for (int kk = 0; kk < 2; kk++) {
        bf16x8 bk = *(const bf16x8*)&Kl[cur][nt * 16 + lr][kk * 32 + lg * 8];
        sacc[nt] = __builtin_amdgcn_mfma_f32_16x16x32_bf16(bk, aq[kk], sacc[nt], 0, 0, 0);
      }
    }

    // lane-local softmax (base-2)
    float pm;
    {
      float a0 = fmaxf(fmaxf(sacc[0][0], sacc[0][1]), fmaxf(sacc[0][2], sacc[0][3]));
      float a1 = fmaxf(fmaxf(sacc[1][0], sacc[1][1]), fmaxf(sacc[1][2], sacc[1][3]));
      float a2 = fmaxf(fmaxf(sacc[2][0], sacc[2][1]), fmaxf(sacc[2][2], sacc[2][3]));
      float a3 = fmaxf(fmaxf(sacc[3][0], sacc[3][1]), fmaxf(sacc[3][2], sacc[3][3]));
      pm = fmaxf(fmaxf(a0, a1), fmaxf(a2, a3)) * c2;
    }
    pm = fmaxf(pm, __shfl_xor(pm, 16));
    pm = fmaxf(pm, __shfl_xor(pm, 32));

    // T13 defer-max
    if (!__all((int)(pm <= m2 + 8.f))) {
      float mn = fmaxf(m2, pm);
      float corr = fexp2(m2 - mn);
      m2 = mn;
      lsum *= corr;
#pragma unroll
      for (int dt = 0; dt < 4; dt++) {
        f32x4 tmp = o[dt];
        tmp[0] *= corr; tmp[1] *= corr; tmp[2] *= corr; tmp[3] *= corr;
        o[dt] = tmp;
      }
    }

    float p[4][4];
    float rs = 0.f;
#pragma unroll
    for (int nt = 0; nt < 4; nt++)
#pragma unroll
      for (int r = 0; r < 4; r++) {
        float v = fexp2(fmaf(sacc[nt][r], c2, -m2));
        p[nt][r] = v;
        rs += v;
      }
    rs += __shfl_xor(rs, 16);
    rs += __shfl_xor(rs, 32);
    lsum += rs;

    // pack P -> PT[q][key] (per-wave; intra-wave in-order LDS, no barrier)
#pragma unroll
    for (int nt = 0; nt < 4; nt++)
#pragma unroll
      for (int c = 0; c < 2; c++)
        *(unsigned int*)&PT[wave][lr][nt * 16 + lg * 4 + 2 * c] =
            cvtpk_bf16(p[nt][2 * c], p[nt][2 * c + 1]);

    bf16x8 ap[2];
#pragma unroll
    for (int ks = 0; ks < 2; ks++)
      ap[ks] = *(const bf16x8*)&PT[wave][lr][ks * 32 + lg * 8];

    // PV: O^T += V^T * P^T.  A-frags via hw transpose reads:
    // subtile (kq = ks*8 + lg*2 + c, dt) at byte ks*4096 + lg*1024 + c*512 + dt*128;
    // column d=lr selected by slot offset lr*8.
    unsigned vb = (cur ? vbuf1 : vbuf0) + vtr_lane;
    union { bf16x8 v; s16x4 h[2]; } bv[4][2];
#pragma unroll
    for (int dt = 0; dt < 4; dt++)
#pragma unroll
      for (int ks = 0; ks < 2; ks++) {
        tr16(vb + ks * 4096 + 0 * 512 + dt * 128, bv[dt][ks].h[0]);
        tr16(vb + ks * 4096 + 1 * 512 + dt * 128, bv[dt][ks].h[1]);
      }
    asm volatile("s_waitcnt lgkmcnt(0)" ::: "memory");
    __builtin_amdgcn_sched_barrier(0);
#pragma unroll
    for (int dt = 0; dt < 4; dt++)
#pragma unroll
      for (int ks = 0; ks < 2; ks++)
        o[dt] = __builtin_amdgcn_mfma_f32_16x16x32_bf16(bv[dt][ks].v, ap[ks], o[dt], 0, 0, 0);
    // no trailing barrier: next tile writes the other buffer
  }

  // epilogue: normalize, transpose O via PT, coalesced write
  float inv = 1.f / lsum;
#pragma unroll
  for (int dt = 0; dt < 4; dt++)
#pragma unroll
    for (int c = 0; c < 2; c++)
      *(unsigned int*)&PT[wave][lr][dt * 16 + lg * 4 + 2 * c] =
          cvtpk_bf16(o[dt][2 * c] * inv, o[dt][2 * c + 1] * inv);

  int row = lane >> 2, cs = lane & 3;
  bf16x8 w0 = *(const bf16x8*)&PT[wave][row][cs * 16];
  bf16x8 w1 = *(const bf16x8*)&PT[wave][row][cs * 16 + 8];
  size_t base = ((size_t)(b * SEQ + q0 + row)) * 512 + h * 64 + cs * 16;
  *(bf16x8*)(CTX + base) = w0;
  *(bf16x8*)(CTX + base + 8) = w1;
}

// ---------------- launch ----------------

extern "C" void kernel_launch(void* const* d_in, const int* in_sizes, int n_in,
                              void* d_out, int out_size, void* d_ws, size_t ws_size,
                              hipStream_t stream) {
  const float* X  = (const float*)d_in[0];
  const float* Wq = (const float*)d_in[1];
  const float* Wk = (const float*)d_in[2];
  const float* Wv = (const float*)d_in[3];
  const float* Wo = (const float*)d_in[4];
  float* out = (float*)d_out;

  char* ws = (char*)d_ws;
  unsigned short* Wqt = (unsigned short*)(ws);
  unsigned short* Wot = (unsigned short*)(ws + 3u * 524288u);
  unsigned short* Xb  = (unsigned short*)(ws + 4u * 524288u);
  unsigned short* Qb  = (unsigned short*)(ws + 4u * 524288u + 8388608u);
  unsigned short* Kb  = Qb + (size_t)MTOT * 512;
  unsigned short* Vb  = Kb + (size_t)MTOT * 512;
  unsigned short* CTX = Vb + (size_t)MTOT * 512;

  int nX = MTOT * D_MODEL;
  cvt_x_kernel<<<dim3(nX / (8 * 256)), dim3(256), 0, stream>>>(X, Xb, nX);
  cvt_w_kernel<<<dim3(1024, 4), dim3(256), 0, stream>>>(Wq, Wk, Wv, Wo, Wqt);
  gemm128_kernel<<<dim3(64, 4, 3), dim3(256), 0, stream>>>(Xb, Wqt, Qb, nullptr, -1);
  attn_kernel<<<dim3(512), dim3(512), 0, stream>>>(Qb, Kb, Vb, CTX);
  gemm128_kernel<<<dim3(64, 4, 1), dim3(256), 0, stream>>>(CTX, Wot, nullptr, out, 3);
}